// Round 6
// baseline (415.365 us; speedup 1.0000x reference)
//
#include <hip/hip_runtime.h>

#define TOKENS 2048
#define HIDDEN 2048
#define INTER  768
#define NEXP   16
#define NA     (TOKENS * 2)
#define MTILE  128
#define MAXT   64

typedef unsigned int   uint32;
typedef unsigned short u16;
typedef __bf16 bf16x8 __attribute__((ext_vector_type(8)));
typedef float  f32x4  __attribute__((ext_vector_type(4)));

__device__ __forceinline__ u16 f2bf(float f) {
    union { float f; uint32 u; } v; v.f = f;
    return (u16)((v.u + 0x7fffu + ((v.u >> 16) & 1u)) >> 16);
}
// fast pack of two fp32 -> two bf16 (round-half-away; plenty for 2% threshold)
__device__ __forceinline__ uint32 pk2(float a, float b) {
    union { float f; uint32 u; } x, y; x.f = a; y.f = b;
    return ((x.u + 0x8000u) >> 16) | ((y.u + 0x8000u) & 0xffff0000u);
}
__device__ __forceinline__ uint4 cvt8f(float4 a, float4 b) {
    uint4 o;
    o.x = pk2(a.x, a.y); o.y = pk2(a.z, a.w);
    o.z = pk2(b.x, b.y); o.w = pk2(b.z, b.w);
    return o;
}
// 16B-unit index into a row-major (rowstride 64 bf16) LDS tile, XOR-swizzled
__device__ __forceinline__ int swz(int row, int k8) { return row * 8 + (k8 ^ (row & 7)); }

__device__ __forceinline__ f32x4 mfma16(bf16x8 a, bf16x8 b, f32x4 c) {
    return __builtin_amdgcn_mfma_f32_16x16x32_bf16(a, b, c, 0, 0, 0);
}

// ---------------- prep: X fp32->bf16, zero out, route (block 0) ----------------
__global__ void prep_kernel(const float* __restrict__ X, u16* __restrict__ Xb,
                            float* __restrict__ out,
                            const int* __restrict__ idx, int* __restrict__ meta,
                            int* __restrict__ bucket) {
    const int gid = blockIdx.x * 256 + threadIdx.x;
    // X convert: 8 floats/thread
    const float4* s = (const float4*)X + (size_t)gid * 2;
    ((uint4*)Xb)[gid] = cvt8f(s[0], s[1]);
    // zero out: 8 floats/thread (2048 blocks x 256 thr x 8 = TOKENS*HIDDEN)
    float4* o = (float4*)out + (size_t)gid * 2;
    const float4 z = {0.f, 0.f, 0.f, 0.f};
    o[0] = z; o[1] = z;
    // routing: block 0 only (uniform branch; block-local barriers are legal)
    if (blockIdx.x == 0) {
        __shared__ int scnt[NEXP];
        __shared__ int soff[NEXP + 1];
        __shared__ int sfill[NEXP];
        __shared__ int sflag;
        const int tid = threadIdx.x;
        if (tid < NEXP) { scnt[tid] = 0; sfill[tid] = 0; }
        if (tid == 0) sflag = 0;
        __syncthreads();
        // int64-vs-int32 probe: int64 buffer has all-zero odd words
        int any = 0;
        for (int a = tid; a < NA / 2; a += 256) any |= idx[2 * a + 1];
        if (any) atomicOr(&sflag, 1);
        __syncthreads();
        const int stride = sflag ? 1 : 2;
        for (int a = tid; a < NA; a += 256) atomicAdd(&scnt[idx[a * stride]], 1);
        __syncthreads();
        if (tid == 0) {
            int s2 = 0;
            for (int e = 0; e < NEXP; ++e) { soff[e] = s2; s2 += scnt[e]; }
            soff[NEXP] = s2;
            int nt = 0;
            for (int e = 0; e < NEXP; ++e) {
                const int ne = soff[e + 1] - soff[e];
                for (int m0 = 0; m0 < ne; m0 += MTILE) {
                    meta[32 + nt] = e;      // tile expert
                    meta[96 + nt] = m0;     // tile m0
                    ++nt;
                }
            }
            meta[17] = nt;
        }
        __syncthreads();
        for (int a = tid; a < NA; a += 256) {
            int e = idx[a * stride];
            int slot = atomicAdd(&sfill[e], 1);
            bucket[soff[e] + slot] = a;   // assignment id; token = a>>1
        }
        if (tid <= NEXP) meta[tid] = soff[tid];
    }
}

// ---------------- GEMM1: gate/up + SwiGLU -> H (slot-ordered, bf16) ----------------
// block: 128 slots x 64 inter-cols. Weights staged 4 k-tiles deep (1 KB contiguous
// per weight row per touch -> DRAM page efficiency). X (L3-resident bf16) is read
// per-lane directly from global as A-fragments: no Xs tile, 2 barriers per 256-k.
__global__ __launch_bounds__(256, 4) void gemm1_kernel(
    const u16* __restrict__ Xb,    // [TOKENS, HIDDEN] bf16
    const float* __restrict__ Wg,  // [NEXP, INTER, HIDDEN] fp32
    const float* __restrict__ Wu,  // [NEXP, INTER, HIDDEN] fp32
    const int* __restrict__ meta, const int* __restrict__ bucket,
    u16* __restrict__ Hbuf)        // [NA, INTER] bf16, slot-ordered
{
    const int ty = blockIdx.y;
    if (ty >= meta[17]) return;
    const int e    = meta[32 + ty];
    const int m0   = meta[96 + ty];
    const int j0   = blockIdx.x * 64;
    const int base = meta[e];
    const int ne   = meta[e + 1] - base;

    __shared__ u16 Gs[4][64 * 64];   // 32 KB
    __shared__ u16 Us[4][64 * 64];   // 32 KB  -> 64 KB total

    const int tid  = threadIdx.x;
    const int lane = tid & 63;
    const int wm   = (tid >> 6) * 32;
    const int lr   = lane & 15;
    const int lq   = lane >> 4;
    const int srow = tid >> 3;    // 0..31 weight staging row
    const int c8   = tid & 7;     // 0..7  staging chunk

    // per-lane A-row pointers (this lane's 2 output rows)
    int sa = m0 + wm + lr;       sa = sa < ne ? sa : ne - 1;
    int sb = m0 + wm + 16 + lr;  sb = sb < ne ? sb : ne - 1;
    const u16* xa = Xb + (size_t)(bucket[base + sa] >> 1) * HIDDEN;
    const u16* xc = Xb + (size_t)(bucket[base + sb] >> 1) * HIDDEN;

    const float* g0p = Wg + ((size_t)e * INTER + j0 + srow) * HIDDEN;
    const float* g1p = g0p + (size_t)32 * HIDDEN;
    const float* u0p = Wu + ((size_t)e * INTER + j0 + srow) * HIDDEN;
    const float* u1p = u0p + (size_t)32 * HIDDEN;

    f32x4 ag[2][4] = {};
    f32x4 au[2][4] = {};

    for (int k0 = 0; k0 < HIDDEN; k0 += 256) {
        __syncthreads();
        // stage 4 k-tiles of weights; per wave each row's [k0,k0+256) floats are
        // covered densely (t-chunks at stride 256B, union = 1KB contiguous).
#pragma unroll
        for (int t = 0; t < 4; ++t) {
            const int cg = (c8 + 8 * t) * 8;   // float offset in 256-float stripe
            const float4* a0 = (const float4*)(g0p + k0 + cg);
            *(uint4*)(Gs[t] + swz(srow, c8) * 8)      = cvt8f(a0[0], a0[1]);
            const float4* a1 = (const float4*)(g1p + k0 + cg);
            *(uint4*)(Gs[t] + swz(srow + 32, c8) * 8) = cvt8f(a1[0], a1[1]);
            const float4* b0 = (const float4*)(u0p + k0 + cg);
            *(uint4*)(Us[t] + swz(srow, c8) * 8)      = cvt8f(b0[0], b0[1]);
            const float4* b1 = (const float4*)(u1p + k0 + cg);
            *(uint4*)(Us[t] + swz(srow + 32, c8) * 8) = cvt8f(b1[0], b1[1]);
        }
        __syncthreads();
        // 4 MFMA sub-phases, no barriers (weights read-only until next outer sync)
#pragma unroll
        for (int t = 0; t < 4; ++t) {
#pragma unroll
            for (int kk = 0; kk < 2; ++kk) {
                const int k8 = kk * 4 + lq;
                const int xoff = k0 + t * 64 + k8 * 8;
                const bf16x8 af0 = *(const bf16x8*)(xa + xoff);
                const bf16x8 af1 = *(const bf16x8*)(xc + xoff);
                bf16x8 bg[4], bu[4];
#pragma unroll
                for (int j = 0; j < 4; ++j) {
                    bg[j] = *(const bf16x8*)(Gs[t] + swz(j * 16 + lr, k8) * 8);
                    bu[j] = *(const bf16x8*)(Us[t] + swz(j * 16 + lr, k8) * 8);
                }
#pragma unroll
                for (int j = 0; j < 4; ++j) {
                    ag[0][j] = mfma16(af0, bg[j], ag[0][j]);
                    ag[1][j] = mfma16(af1, bg[j], ag[1][j]);
                    au[0][j] = mfma16(af0, bu[j], au[0][j]);
                    au[1][j] = mfma16(af1, bu[j], au[1][j]);
                }
            }
        }
    }
    // epilogue: h = silu(g)*u ; C layout col=lane&15, row=lq*4+r
#pragma unroll
    for (int i = 0; i < 2; ++i)
#pragma unroll
        for (int r = 0; r < 4; ++r) {
            const int slot = m0 + wm + i * 16 + lq * 4 + r;
            if (slot < ne) {
#pragma unroll
                for (int j = 0; j < 4; ++j) {
                    const float g = ag[i][j][r];
                    const float u = au[i][j][r];
                    const float h = (g / (1.f + __expf(-g))) * u;
                    Hbuf[(size_t)(base + slot) * INTER + j0 + j * 16 + lr] = f2bf(h);
                }
            }
        }
}

// ---------------- GEMM2: down-proj -> weighted atomicAdd into out ----------------
// block: 128 slots x 64 hidden-cols. Wd staged 2 k-tiles deep (512B/row/touch);
// H (L3-resident bf16) read per-lane directly from global as A-fragments.
__global__ __launch_bounds__(256, 4) void gemm2_kernel(
    const u16* __restrict__ Hbuf,   // [NA, INTER] bf16, slot-ordered
    const float* __restrict__ Wd,   // [NEXP, HIDDEN, INTER] fp32
    const float* __restrict__ tkw,  // [TOKENS, 2] fp32
    const int* __restrict__ meta, const int* __restrict__ bucket,
    float* __restrict__ out)        // [TOKENS, HIDDEN] fp32, pre-zeroed
{
    const int ty = blockIdx.y;
    if (ty >= meta[17]) return;
    const int e    = meta[32 + ty];
    const int m0   = meta[96 + ty];
    const int n0   = blockIdx.x * 64;
    const int base = meta[e];
    const int ne   = meta[e + 1] - base;

    __shared__ u16 Ds[2][64 * 64];   // 16 KB

    const int tid  = threadIdx.x;
    const int lane = tid & 63;
    const int wm   = (tid >> 6) * 32;
    const int lr   = lane & 15;
    const int lq   = lane >> 4;
    const int srow = tid >> 3;
    const int c8   = tid & 7;

    int sa = m0 + wm + lr;       sa = sa < ne ? sa : ne - 1;
    int sb = m0 + wm + 16 + lr;  sb = sb < ne ? sb : ne - 1;
    const u16* ha = Hbuf + (size_t)(base + sa) * INTER;
    const u16* hb = Hbuf + (size_t)(base + sb) * INTER;

    const float* d0p = Wd + ((size_t)e * HIDDEN + n0 + srow) * INTER;
    const float* d1p = d0p + (size_t)32 * INTER;

    f32x4 ac[2][4] = {};

    for (int k0 = 0; k0 < INTER; k0 += 128) {
        __syncthreads();
#pragma unroll
        for (int t = 0; t < 2; ++t) {
            const int cg = (c8 + 8 * t) * 8;
            const float4* a0 = (const float4*)(d0p + k0 + cg);
            *(uint4*)(Ds[t] + swz(srow, c8) * 8)      = cvt8f(a0[0], a0[1]);
            const float4* a1 = (const float4*)(d1p + k0 + cg);
            *(uint4*)(Ds[t] + swz(srow + 32, c8) * 8) = cvt8f(a1[0], a1[1]);
        }
        __syncthreads();
#pragma unroll
        for (int t = 0; t < 2; ++t) {
#pragma unroll
            for (int kk = 0; kk < 2; ++kk) {
                const int k8 = kk * 4 + lq;
                const int xoff = k0 + t * 64 + k8 * 8;
                const bf16x8 af0 = *(const bf16x8*)(ha + xoff);
                const bf16x8 af1 = *(const bf16x8*)(hb + xoff);
                bf16x8 bd[4];
#pragma unroll
                for (int j = 0; j < 4; ++j)
                    bd[j] = *(const bf16x8*)(Ds[t] + swz(j * 16 + lr, k8) * 8);
#pragma unroll
                for (int j = 0; j < 4; ++j) {
                    ac[0][j] = mfma16(af0, bd[j], ac[0][j]);
                    ac[1][j] = mfma16(af1, bd[j], ac[1][j]);
                }
            }
        }
    }
#pragma unroll
    for (int i = 0; i < 2; ++i)
#pragma unroll
        for (int r = 0; r < 4; ++r) {
            const int slot = m0 + wm + i * 16 + lq * 4 + r;
            if (slot < ne) {
                const int a = bucket[base + slot];
                const int t = a >> 1;
                const float w = tkw[a];
#pragma unroll
                for (int j = 0; j < 4; ++j)
                    atomicAdd(out + (size_t)t * HIDDEN + n0 + j * 16 + lr, w * ac[i][j][r]);
            }
        }
}

extern "C" void kernel_launch(void* const* d_in, const int* in_sizes, int n_in,
                              void* d_out, int out_size, void* d_ws, size_t ws_size,
                              hipStream_t stream) {
    const float* X   = (const float*)d_in[0];
    const int*   idx = (const int*)d_in[1];
    const float* tkw = (const float*)d_in[2];
    const float* Wg  = (const float*)d_in[3];
    const float* Wu  = (const float*)d_in[4];
    const float* Wd  = (const float*)d_in[5];
    float* out = (float*)d_out;

    char* ws = (char*)d_ws;
    int* meta   = (int*)ws;                     // off[0..16], ntiles[17], tileE[32..], tileM0[96..]
    int* bucket = (int*)(ws + 1024);            // 4096 ints
    u16* Xb     = (u16*)(ws + 32768);           // 8.39 MB
    u16* Hbuf   = (u16*)(ws + 32768 + (size_t)TOKENS * HIDDEN * 2);  // 6.29 MB

    prep_kernel<<<TOKENS * HIDDEN / 8 / 256, 256, 0, stream>>>(X, Xb, out, idx, meta, bucket);
    dim3 g1(INTER / 64, MAXT);
    gemm1_kernel<<<g1, 256, 0, stream>>>(Xb, Wg, Wu, meta, bucket, Hbuf);
    dim3 g2(HIDDEN / 64, MAXT);
    gemm2_kernel<<<g2, 256, 0, stream>>>(Hbuf, Wd, tkw, meta, bucket, out);
}